// Round 3
// baseline (1276.853 us; speedup 1.0000x reference)
//
#include <hip/hip_runtime.h>

typedef float f32x4 __attribute__((ext_vector_type(4)));
typedef short s16x8 __attribute__((ext_vector_type(8)));
typedef unsigned uint4v __attribute__((ext_vector_type(4)));

#define HH   768
#define SS   256
#define GR   8     // row groups (16 rows each); g = blockIdx & 7
#define GP   24    // col blocks per group; p = blockIdx >> 3
#define NROW 128
#define LDP  776   // LDS row pitch (shorts); 1552B = 16B-aligned rows
#define PP   68    // partials row pitch (floats)

__device__ __forceinline__ unsigned short f2bf(float f) {
  unsigned int u = __float_as_uint(f);
  u += 0x7FFFu + ((u >> 16) & 1u);          // RTNE
  return (unsigned short)(u >> 16);
}
__device__ __forceinline__ float bf2f(unsigned short s) {
  return __uint_as_float(((unsigned int)s) << 16);
}
__device__ __forceinline__ float sigm(float v) { return 1.0f / (1.0f + __expf(-v)); }
__device__ __forceinline__ float tanhf_(float v) {
  return 1.0f - 2.0f / (__expf(2.0f * v) + 1.0f);
}

// 192 blocks x 512 threads (8 waves, 2/SIMD via launch_bounds(512,2)).
// Static roles: g = blockIdx&7 (rows [16g,16g+16)), p = blockIdx>>3 (hidden
// cols [32p,32p+32)); gate cols permuted col = hcol*4 + gate.
// Wave w: colh = w&1 (64-gate-col half), ks = w>>1 (6-kt slice of K).
//   => B-frags 6kt x 4n x hi/lo (AGPR-side); merged f32 acc (hh+hl+lh chained
//   into one accumulator) = 16 VGPR.
// R10: fast path loads A-fragments DIRECTLY global->VGPR (16B loads from the
// XCD L2: lane frag = h[(row_base+l15)*768 + kt*32 + quad*8], 16B-aligned,
// contiguous) — LDS staging + its __syncthreads + 12 ds_read_b128/lane
// removed from the critical path. Lines touched = the same 48KB slice the
// staging read, so the R6 L1-capacity-eviction staleness argument holds
// (>=48KB/step streamed through 32KB L1, x3 parities). Slow path keeps LDS
// staging verbatim.
// Partials: LDS [colh][ks][16][PP], reduced over ks by 512 threads (1 cell
// each); bias + x*w0 added at reduction from LDS tables.
// Transport/sync: R6-proven verbatim — XCC_ID vote gating write-through
// stores + plain loads in the XCD L2 (3 parities defeat stale L1), agent-
// scope counter barrier (R9's sc0 self-release barrier hung on HW twice;
// reverted).
__global__ void __launch_bounds__(512, 2) lstm_persistent(
    const float* __restrict__ xin, const float* __restrict__ h0,
    const float* __restrict__ c0,
    const float* __restrict__ Wi, const float* __restrict__ bi,
    const float* __restrict__ Wf, const float* __restrict__ bfv,
    const float* __restrict__ Wc, const float* __restrict__ bc,
    const float* __restrict__ Wo, const float* __restrict__ bo,
    const float* __restrict__ Wout, const float* __restrict__ bout,
    float* __restrict__ out,
    unsigned short* __restrict__ hhi0, unsigned short* __restrict__ hhi1,
    unsigned short* __restrict__ hhi2,
    unsigned short* __restrict__ hlo0, unsigned short* __restrict__ hlo1,
    unsigned short* __restrict__ hlo2,
    unsigned* __restrict__ bar)
{
  const int tid = threadIdx.x, wave = tid >> 6, lane = tid & 63;
  const int l15 = lane & 15, quad = lane >> 4;
  const int g = blockIdx.x & 7, p = blockIdx.x >> 3;
  const int row_base = g * 16, hcol_base = p * 32;
  const int colh = wave & 1, ks = wave >> 1;   // col-half / kt-slice

  __shared__ __align__(16) unsigned short lds_hi[16 * LDP];
  __shared__ __align__(16) unsigned short lds_lo[16 * LDP];
  __shared__ __align__(16) float part[2][4][16][PP];   // [colh][ks][row][col64]
  __shared__ float bw_b[128], bw_w[128];               // bias / x-weight per col
  __shared__ float c_lds[16][33];
  __shared__ float x_lds[16];
  __shared__ int s_fast;

  unsigned* ctr = bar + g * 64;              // step barrier (256B-spaced)
  unsigned* rdy = bar + 512 + g * 16;        // rendezvous counter
  unsigned* ids = bar + 640 + g * 32;        // 24 published XCC_IDs

  // ---- one-time vote (tid0): all 24 members on one XCD? [R6-proven] ----
  if (tid == 0) {
    const unsigned my = (__builtin_amdgcn_s_getreg(20 | (3 << 11)) & 15u) + 1u;
    __hip_atomic_store(ids + p, my, __ATOMIC_RELAXED, __HIP_MEMORY_SCOPE_AGENT);
    __hip_atomic_fetch_add(rdy, 1u, __ATOMIC_RELEASE, __HIP_MEMORY_SCOPE_AGENT);
    while (__hip_atomic_load(rdy, __ATOMIC_ACQUIRE, __HIP_MEMORY_SCOPE_AGENT)
           < (unsigned)GP)
      __builtin_amdgcn_s_sleep(8);
    int ok = 1;
    for (int q = 0; q < GP; ++q)
      ok &= (__hip_atomic_load(ids + q, __ATOMIC_RELAXED,
                               __HIP_MEMORY_SCOPE_AGENT) == my);
    s_fast = ok;
  }

  // ---- one-time: weights -> bf16 hi/lo B-fragments (n=lane&15, k=quad*8+j) --
  s16x8 Bhi[6][4], Blo[6][4];
#pragma unroll
  for (int n = 0; n < 4; ++n) {
    const int col = p * 128 + colh * 64 + n * 16 + l15;  // permuted gate col
    const int gg = col & 3, hc = col >> 2;
    const float* W = (gg == 0) ? Wi : (gg == 1) ? Wf : (gg == 2) ? Wc : Wo;
#pragma unroll
    for (int ktl = 0; ktl < 6; ++ktl) {
      const int kt = ks * 6 + ktl;
      s16x8 vh, vl;
#pragma unroll
      for (int j = 0; j < 8; ++j) {
        const int k = kt * 32 + quad * 8 + j;
        const float w = W[(1 + k) * HH + hc];
        const unsigned short hi = f2bf(w);
        vh[j] = (short)hi;
        vl[j] = (short)f2bf(w - bf2f(hi));
      }
      Bhi[ktl][n] = vh; Blo[ktl][n] = vl;
    }
  }

  // ---- one-time: bias + x-weight tables -> LDS (per permuted gate col) ----
  if (tid < 128) {
    const int gg = tid & 3;
    const int hc = p * 32 + (tid >> 2);
    const float* W  = (gg == 0) ? Wi : (gg == 1) ? Wf : (gg == 2) ? Wc : Wo;
    const float* bb = (gg == 0) ? bi : (gg == 1) ? bfv : (gg == 2) ? bc : bo;
    bw_b[tid] = bb[hc];
    bw_w[tid] = W[hc];                       // W row 0 = x weight (exact fp32)
  }

  // ---- init: c->LDS; h0 -> parity-0 buffers (agent stores, proto-neutral) --
  if (tid < 256) {
    const int lr = tid >> 4, lc = (tid & 15) * 2;
    const int gidx = (row_base + lr) * HH + hcol_base + lc;
    const float ha = h0[gidx], hb = h0[gidx + 1];
    c_lds[lr][lc]     = c0[gidx];
    c_lds[lr][lc + 1] = c0[gidx + 1];
    const unsigned short ha_hi = f2bf(ha), hb_hi = f2bf(hb);
    const unsigned short ha_lo = f2bf(ha - bf2f(ha_hi));
    const unsigned short hb_lo = f2bf(hb - bf2f(hb_hi));
    __hip_atomic_store((unsigned*)hhi0 + (gidx >> 1),
                       (unsigned)ha_hi | ((unsigned)hb_hi << 16),
                       __ATOMIC_RELAXED, __HIP_MEMORY_SCOPE_AGENT);
    __hip_atomic_store((unsigned*)hlo0 + (gidx >> 1),
                       (unsigned)ha_lo | ((unsigned)hb_lo << 16),
                       __ATOMIC_RELAXED, __HIP_MEMORY_SCOPE_AGENT);
    if (tid < 16) {
      const int row = row_base + tid;
      x_lds[tid] = xin[(row >> 1) * (SS * 2) + (row & 1)];   // t = 0
    }
  }
  __syncthreads();                           // s_fast + LDS init visible
  const bool fast = (s_fast != 0);
  unsigned bars = 0;

  // Agent-scope counter barrier (R3/R6-proven; R8/R9 variants regressed/hung).
  auto gbar = [&]() {
    __builtin_amdgcn_s_waitcnt(0);
    __syncthreads();
    if (tid == 0) {
      ++bars;
      __hip_atomic_fetch_add(ctr, 1u, __ATOMIC_RELAXED, __HIP_MEMORY_SCOPE_AGENT);
      const unsigned want = (unsigned)GP * bars;
      while (__hip_atomic_load(ctr, __ATOMIC_RELAXED, __HIP_MEMORY_SCOPE_AGENT) < want)
        __builtin_amdgcn_s_sleep(1);
    }
    __syncthreads();
  };

  gbar();                                    // h0/c0 published

  const unsigned short* hbhi[3] = {hhi0, hhi1, hhi2};
  const unsigned short* hblo[3] = {hlo0, hlo1, hlo2};
  unsigned short* wbhi[3] = {hhi0, hhi1, hhi2};
  unsigned short* wblo[3] = {hlo0, hlo1, hlo2};

  const int frag_off = l15 * LDP + quad * 8; // A-frag LDS offset (shorts, slow)
  const int arow_off = (row_base + l15) * HH + quad * 8;  // A-frag global (fast)
  const int lr_c = tid >> 5, lc_c = tid & 31;        // elementwise cell
  const int ch_c = lc_c >> 4, c4_c = (lc_c & 15) * 4;
  int cur = 0;

  for (int t = 0; t < SS; ++t) {
    const int nxt = (cur == 2) ? 0 : cur + 1;
    const unsigned short* rhi = hbhi[cur];
    const unsigned short* rlo = hblo[cur];
    unsigned short* whi = wbhi[nxt];
    unsigned short* wlo = wblo[nxt];

    f32x4 acc[4] = {{0,0,0,0},{0,0,0,0},{0,0,0,0},{0,0,0,0}};

    if (fast) {
      // ---- GEMM, A direct from XCD L2 (no LDS staging, no extra barrier) --
      const unsigned short* aph = rhi + arow_off;
      const unsigned short* apl = rlo + arow_off;
#pragma unroll
      for (int ktl = 0; ktl < 6; ++ktl) {
        const int kt = ks * 6 + ktl;
        const s16x8 ah = *(const s16x8*)(aph + kt * 32);
        const s16x8 al = *(const s16x8*)(apl + kt * 32);
#pragma unroll
        for (int n = 0; n < 4; ++n) {
          acc[n] = __builtin_amdgcn_mfma_f32_16x16x32_bf16(ah, Bhi[ktl][n], acc[n], 0, 0, 0);
          acc[n] = __builtin_amdgcn_mfma_f32_16x16x32_bf16(ah, Blo[ktl][n], acc[n], 0, 0, 0);
          acc[n] = __builtin_amdgcn_mfma_f32_16x16x32_bf16(al, Bhi[ktl][n], acc[n], 0, 0, 0);
        }
      }
    } else {
      // ---- stage group h-slice (16x768 hi+lo) into LDS (agent/MALL loads) --
      const int u64_base = row_base * 192;
#pragma unroll
      for (int i = 0; i < 6; ++i) {
        const int gi = i * 512 + tid;        // u64 idx in [0,3072)
        const int rr = gi / 192, cc = (gi - rr * 192) * 4;
        const unsigned long long vh = __hip_atomic_load(
            (unsigned long long*)rhi + u64_base + gi, __ATOMIC_RELAXED, __HIP_MEMORY_SCOPE_AGENT);
        const unsigned long long vl = __hip_atomic_load(
            (unsigned long long*)rlo + u64_base + gi, __ATOMIC_RELAXED, __HIP_MEMORY_SCOPE_AGENT);
        *(unsigned long long*)&lds_hi[rr * LDP + cc] = vh;
        *(unsigned long long*)&lds_lo[rr * LDP + cc] = vl;
      }
      __syncthreads();

      // ---- GEMM from LDS: wave (colh,ks): 6kt x 4n, merged f32 acc ----
#pragma unroll
      for (int ktl = 0; ktl < 6; ++ktl) {
        const int kt = ks * 6 + ktl;
        const s16x8 ah = *(const s16x8*)&lds_hi[frag_off + kt * 32];
        const s16x8 al = *(const s16x8*)&lds_lo[frag_off + kt * 32];
#pragma unroll
        for (int n = 0; n < 4; ++n) {
          acc[n] = __builtin_amdgcn_mfma_f32_16x16x32_bf16(ah, Bhi[ktl][n], acc[n], 0, 0, 0);
          acc[n] = __builtin_amdgcn_mfma_f32_16x16x32_bf16(ah, Blo[ktl][n], acc[n], 0, 0, 0);
          acc[n] = __builtin_amdgcn_mfma_f32_16x16x32_bf16(al, Bhi[ktl][n], acc[n], 0, 0, 0);
        }
      }
    }

    // ---- partial write: C/D layout col=l15, row=quad*4+reg ----
#pragma unroll
    for (int n = 0; n < 4; ++n)
#pragma unroll
      for (int reg = 0; reg < 4; ++reg)
        part[colh][ks][quad * 4 + reg][n * 16 + l15] = acc[n][reg];
    __syncthreads();

    // ---- reduce over ks + bias + x*w0; elementwise; h store (1 cell/thr) --
    {
      const f32x4 s0 = *(const f32x4*)&part[ch_c][0][lr_c][c4_c];
      const f32x4 s1 = *(const f32x4*)&part[ch_c][1][lr_c][c4_c];
      const f32x4 s2 = *(const f32x4*)&part[ch_c][2][lr_c][c4_c];
      const f32x4 s3 = *(const f32x4*)&part[ch_c][3][lr_c][c4_c];
      const f32x4 bq = *(const f32x4*)&bw_b[lc_c * 4];
      const f32x4 wq = *(const f32x4*)&bw_w[lc_c * 4];
      const float xv = x_lds[lr_c];
      f32x4 gv = (s0 + s1) + (s2 + s3);
#pragma unroll
      for (int j = 0; j < 4; ++j) gv[j] += bq[j] + xv * wq[j];

      float cc = c_lds[lr_c][lc_c];
      cc = sigm(gv[1]) * cc + sigm(gv[0]) * tanhf_(gv[2]);
      const float hh = gv[3] * tanhf_(cc);   // no sigmoid on o-gate (ref)
      c_lds[lr_c][lc_c] = cc;

      const unsigned short mhi = f2bf(hh);
      const unsigned short mlo = f2bf(hh - bf2f(mhi));
      const unsigned ohi = (unsigned)__shfl_down((int)(unsigned)mhi, 1, 64);
      const unsigned olo = (unsigned)__shfl_down((int)(unsigned)mlo, 1, 64);
      if ((tid & 1) == 0) {                  // lc_c even; neighbor = lc_c+1
        const int gidx = (row_base + lr_c) * HH + hcol_base + lc_c;
        const unsigned ph = (unsigned)mhi | (ohi << 16);
        const unsigned pl = (unsigned)mlo | (olo << 16);
        if (fast) {                          // write-through L1 -> XCD L2
          ((unsigned*)whi)[gidx >> 1] = ph;
          ((unsigned*)wlo)[gidx >> 1] = pl;
        } else {
          __hip_atomic_store((unsigned*)whi + (gidx >> 1), ph, __ATOMIC_RELAXED, __HIP_MEMORY_SCOPE_AGENT);
          __hip_atomic_store((unsigned*)wlo + (gidx >> 1), pl, __ATOMIC_RELAXED, __HIP_MEMORY_SCOPE_AGENT);
        }
      }
      if (tid < 16 && t + 1 < SS) {
        const int row = row_base + tid;
        x_lds[tid] = xin[(row >> 1) * (SS * 2) + (t + 1) * 2 + (row & 1)];
      }
    }
    gbar();
    cur = nxt;
  }

  // ---- output projection: final h in parity cur = 256%3 = 1 ----
  if (p == 0 && tid < 256) {
    const unsigned short* fhi = hbhi[cur];
    const unsigned short* flo = hblo[cur];
    const int rloc = tid >> 4, s = tid & 15;
    const int row = row_base + rloc;
    float sum = 0.0f;
#pragma unroll
    for (int i = 0; i < 12; ++i) {
      const int u = row * 192 + s * 12 + i;  // u64 idx; k0 = s*48 + i*4
      unsigned long long vh, vl;
      if (fast) {                            // fresh in this XCD's L2
        vh = *((const unsigned long long*)fhi + u);
        vl = *((const unsigned long long*)flo + u);
      } else {
        vh = __hip_atomic_load((unsigned long long*)fhi + u, __ATOMIC_RELAXED, __HIP_MEMORY_SCOPE_AGENT);
        vl = __hip_atomic_load((unsigned long long*)flo + u, __ATOMIC_RELAXED, __HIP_MEMORY_SCOPE_AGENT);
      }
#pragma unroll
      for (int j = 0; j < 4; ++j) {
        const float h = bf2f((unsigned short)(vh >> (16 * j))) +
                        bf2f((unsigned short)(vl >> (16 * j)));
        sum += h * Wout[s * 48 + i * 4 + j];
      }
    }
#pragma unroll
    for (int off = 8; off; off >>= 1) sum += __shfl_down(sum, off, 16);
    if (s == 0) out[row] = sum + bout[0];
  }
}

extern "C" void kernel_launch(void* const* d_in, const int* in_sizes, int n_in,
                              void* d_out, int out_size, void* d_ws, size_t ws_size,
                              hipStream_t stream) {
  const float* xin  = (const float*)d_in[0];
  const float* h0   = (const float*)d_in[1];
  const float* c0   = (const float*)d_in[2];
  const float* Wi   = (const float*)d_in[3];
  const float* bi   = (const float*)d_in[4];
  const float* Wf   = (const float*)d_in[5];
  const float* bfv  = (const float*)d_in[6];
  const float* Wc   = (const float*)d_in[7];
  const float* bc   = (const float*)d_in[8];
  const float* Wo   = (const float*)d_in[9];
  const float* bo   = (const float*)d_in[10];
  const float* Wout = (const float*)d_in[11];
  const float* bout = (const float*)d_in[12];
  float* out = (float*)d_out;

  char* ws = (char*)d_ws;
  const size_t HB = (size_t)NROW * HH * sizeof(unsigned short);  // 196608
  unsigned short* hhi0 = (unsigned short*)(ws);
  unsigned short* hhi1 = (unsigned short*)(ws + HB);
  unsigned short* hhi2 = (unsigned short*)(ws + 2 * HB);
  unsigned short* hlo0 = (unsigned short*)(ws + 3 * HB);
  unsigned short* hlo1 = (unsigned short*)(ws + 4 * HB);
  unsigned short* hlo2 = (unsigned short*)(ws + 5 * HB);
  unsigned*       bar  = (unsigned*)(ws + 6 * HB);

  hipMemsetAsync(bar, 0, 4096, stream);    // zero barrier/rendezvous counters

  (void)in_sizes; (void)n_in; (void)out_size; (void)ws_size;
  hipLaunchKernelGGL(lstm_persistent, dim3(GR * GP), dim3(512), 0, stream,
                     xin, h0, c0, Wi, bi, Wf, bfv, Wc, bc, Wo, bo,
                     Wout, bout, out, hhi0, hhi1, hhi2, hlo0, hlo1, hlo2, bar);
}

// Round 4
// 1146.492 us; speedup vs baseline: 1.1137x; 1.1137x over previous
//
#include <hip/hip_runtime.h>

typedef float f32x4 __attribute__((ext_vector_type(4)));
typedef short s16x8 __attribute__((ext_vector_type(8)));
typedef unsigned uint4v __attribute__((ext_vector_type(4)));

#define HH   768
#define SS   256
#define GR   8     // row groups (16 rows each); g = blockIdx & 7
#define GP   24    // col blocks per group; p = blockIdx >> 3
#define NROW 128
#define LDP  776   // LDS row pitch (shorts); 1552B = 16B-aligned rows
#define PP   68    // partials row pitch (floats)

__device__ __forceinline__ unsigned short f2bf(float f) {
  unsigned int u = __float_as_uint(f);
  u += 0x7FFFu + ((u >> 16) & 1u);          // RTNE
  return (unsigned short)(u >> 16);
}
__device__ __forceinline__ float bf2f(unsigned short s) {
  return __uint_as_float(((unsigned int)s) << 16);
}
__device__ __forceinline__ float sigm(float v) { return 1.0f / (1.0f + __expf(-v)); }
__device__ __forceinline__ float tanhf_(float v) {
  return 1.0f - 2.0f / (__expf(2.0f * v) + 1.0f);
}

// 192 blocks x 512 threads (8 waves, 2/SIMD via launch_bounds(512,2)).
// Static roles: g = blockIdx&7 (rows [16g,16g+16)), p = blockIdx>>3 (hidden
// cols [32p,32p+32)); gate cols permuted col = hcol*4 + gate.
// Wave w: colh = w&1, ks = w>>1 (6-kt slice of K).
// R11 (this round):
//  - REVERT R10 direct-L2 A-loads (regressed 968->1277: exposed L2 latency
//    chains; MfmaUtil 20->15). Staged LDS path restored.
//  - Split-phase staging (fast path): issue all 6 staging loads up front;
//    write K<384 half, sync; ks<2 waves (slices fully in K<384) GEMM while
//    the K>=384 load tail lands; write K>=384 half, sync; ks>=2 waves GEMM.
//    One ks01 + one ks23 wave per SIMD -> 360cy MFMA overlaps staging tail.
//  - Barrier poll: sleepless 2-deep pipelined agent-scope loads (same proven
//    atomics/scope; only the poll loop is software-pipelined).
//  - bias/x-weight tables hoisted LDS->regs (syncthreads blocked hoisting).
// Transport/sync: R6-proven verbatim otherwise (XCC_ID vote, write-through
// stores + plain loads in XCD L2, 3 parities, agent-scope counter barrier).
__global__ void __launch_bounds__(512, 2) lstm_persistent(
    const float* __restrict__ xin, const float* __restrict__ h0,
    const float* __restrict__ c0,
    const float* __restrict__ Wi, const float* __restrict__ bi,
    const float* __restrict__ Wf, const float* __restrict__ bfv,
    const float* __restrict__ Wc, const float* __restrict__ bc,
    const float* __restrict__ Wo, const float* __restrict__ bo,
    const float* __restrict__ Wout, const float* __restrict__ bout,
    float* __restrict__ out,
    unsigned short* __restrict__ hhi0, unsigned short* __restrict__ hhi1,
    unsigned short* __restrict__ hhi2,
    unsigned short* __restrict__ hlo0, unsigned short* __restrict__ hlo1,
    unsigned short* __restrict__ hlo2,
    unsigned* __restrict__ bar)
{
  const int tid = threadIdx.x, wave = tid >> 6, lane = tid & 63;
  const int l15 = lane & 15, quad = lane >> 4;
  const int g = blockIdx.x & 7, p = blockIdx.x >> 3;
  const int row_base = g * 16, hcol_base = p * 32;
  const int colh = wave & 1, ks = wave >> 1;   // col-half / kt-slice

  __shared__ __align__(16) unsigned short lds_hi[16 * LDP];
  __shared__ __align__(16) unsigned short lds_lo[16 * LDP];
  __shared__ __align__(16) float part[2][4][16][PP];   // [colh][ks][row][col64]
  __shared__ float bw_b[128], bw_w[128];               // bias / x-weight per col
  __shared__ float c_lds[16][33];
  __shared__ float x_lds[16];
  __shared__ int s_fast;

  unsigned* ctr = bar + g * 64;              // step barrier (256B-spaced)
  unsigned* rdy = bar + 512 + g * 16;        // rendezvous counter
  unsigned* ids = bar + 640 + g * 32;        // 24 published XCC_IDs

  // ---- one-time vote (tid0): all 24 members on one XCD? [R6-proven] ----
  if (tid == 0) {
    const unsigned my = (__builtin_amdgcn_s_getreg(20 | (3 << 11)) & 15u) + 1u;
    __hip_atomic_store(ids + p, my, __ATOMIC_RELAXED, __HIP_MEMORY_SCOPE_AGENT);
    __hip_atomic_fetch_add(rdy, 1u, __ATOMIC_RELEASE, __HIP_MEMORY_SCOPE_AGENT);
    while (__hip_atomic_load(rdy, __ATOMIC_ACQUIRE, __HIP_MEMORY_SCOPE_AGENT)
           < (unsigned)GP)
      __builtin_amdgcn_s_sleep(8);
    int ok = 1;
    for (int q = 0; q < GP; ++q)
      ok &= (__hip_atomic_load(ids + q, __ATOMIC_RELAXED,
                               __HIP_MEMORY_SCOPE_AGENT) == my);
    s_fast = ok;
  }

  // ---- one-time: weights -> bf16 hi/lo B-fragments (n=lane&15, k=quad*8+j) --
  s16x8 Bhi[6][4], Blo[6][4];
#pragma unroll
  for (int n = 0; n < 4; ++n) {
    const int col = p * 128 + colh * 64 + n * 16 + l15;  // permuted gate col
    const int gg = col & 3, hc = col >> 2;
    const float* W = (gg == 0) ? Wi : (gg == 1) ? Wf : (gg == 2) ? Wc : Wo;
#pragma unroll
    for (int ktl = 0; ktl < 6; ++ktl) {
      const int kt = ks * 6 + ktl;
      s16x8 vh, vl;
#pragma unroll
      for (int j = 0; j < 8; ++j) {
        const int k = kt * 32 + quad * 8 + j;
        const float w = W[(1 + k) * HH + hc];
        const unsigned short hi = f2bf(w);
        vh[j] = (short)hi;
        vl[j] = (short)f2bf(w - bf2f(hi));
      }
      Bhi[ktl][n] = vh; Blo[ktl][n] = vl;
    }
  }

  // ---- one-time: bias + x-weight tables -> LDS (per permuted gate col) ----
  if (tid < 128) {
    const int gg = tid & 3;
    const int hc = p * 32 + (tid >> 2);
    const float* W  = (gg == 0) ? Wi : (gg == 1) ? Wf : (gg == 2) ? Wc : Wo;
    const float* bb = (gg == 0) ? bi : (gg == 1) ? bfv : (gg == 2) ? bc : bo;
    bw_b[tid] = bb[hc];
    bw_w[tid] = W[hc];                       // W row 0 = x weight (exact fp32)
  }

  // ---- init: c->LDS; h0 -> parity-0 buffers (agent stores, proto-neutral) --
  if (tid < 256) {
    const int lr = tid >> 4, lc = (tid & 15) * 2;
    const int gidx = (row_base + lr) * HH + hcol_base + lc;
    const float ha = h0[gidx], hb = h0[gidx + 1];
    c_lds[lr][lc]     = c0[gidx];
    c_lds[lr][lc + 1] = c0[gidx + 1];
    const unsigned short ha_hi = f2bf(ha), hb_hi = f2bf(hb);
    const unsigned short ha_lo = f2bf(ha - bf2f(ha_hi));
    const unsigned short hb_lo = f2bf(hb - bf2f(hb_hi));
    __hip_atomic_store((unsigned*)hhi0 + (gidx >> 1),
                       (unsigned)ha_hi | ((unsigned)hb_hi << 16),
                       __ATOMIC_RELAXED, __HIP_MEMORY_SCOPE_AGENT);
    __hip_atomic_store((unsigned*)hlo0 + (gidx >> 1),
                       (unsigned)ha_lo | ((unsigned)hb_lo << 16),
                       __ATOMIC_RELAXED, __HIP_MEMORY_SCOPE_AGENT);
    if (tid < 16) {
      const int row = row_base + tid;
      x_lds[tid] = xin[(row >> 1) * (SS * 2) + (row & 1)];   // t = 0
    }
  }
  __syncthreads();                           // s_fast + LDS init visible
  const bool fast = (s_fast != 0);
  unsigned bars = 0;

  // Hoisted loop-invariant tables (syncthreads prevents compiler hoisting).
  const int lr_c = tid >> 5, lc_c = tid & 31;        // elementwise cell
  const int ch_c = lc_c >> 4, c4_c = (lc_c & 15) * 4;
  const f32x4 bq = *(const f32x4*)&bw_b[lc_c * 4];
  const f32x4 wq = *(const f32x4*)&bw_w[lc_c * 4];

  // Agent-scope counter barrier (R3/R6-proven protocol; poll loop is
  // sleeplessly 2-deep software-pipelined: same atomics, same scope).
  auto gbar = [&]() {
    __builtin_amdgcn_s_waitcnt(0);
    __syncthreads();
    if (tid == 0) {
      ++bars;
      __hip_atomic_fetch_add(ctr, 1u, __ATOMIC_RELAXED, __HIP_MEMORY_SCOPE_AGENT);
      const unsigned want = (unsigned)GP * bars;
      unsigned v0 = __hip_atomic_load(ctr, __ATOMIC_RELAXED, __HIP_MEMORY_SCOPE_AGENT);
      for (;;) {
        unsigned v1 = __hip_atomic_load(ctr, __ATOMIC_RELAXED, __HIP_MEMORY_SCOPE_AGENT);
        if (v0 >= want) break;
        v0 = __hip_atomic_load(ctr, __ATOMIC_RELAXED, __HIP_MEMORY_SCOPE_AGENT);
        if (v1 >= want) break;
      }
    }
    __syncthreads();
  };

  gbar();                                    // h0/c0 published

  const unsigned short* hbhi[3] = {hhi0, hhi1, hhi2};
  const unsigned short* hblo[3] = {hlo0, hlo1, hlo2};
  unsigned short* wbhi[3] = {hhi0, hhi1, hhi2};
  unsigned short* wblo[3] = {hlo0, hlo1, hlo2};

  const int frag_off = l15 * LDP + quad * 8; // A-frag LDS offset (shorts)

  // ---- split-staging precompute (fast path; loop-invariant) ----
  // Enumerate the K<384 half as 1536 u128 (hi rows then lo rows):
  //   u = j*512+tid, buf = u<768?hi:lo, e = u%768, row = e/48, c48 = e%48.
  // Load index in buffer (u128): (row_base+row)*96 + h*48 + c48.
  // LDS short offset: row*LDP + h*384 + c48*8.
  const int u1 = 512 + tid;
  const int bs1 = (u1 >= 768);               // j=0 always hi, j=2 always lo
  const int e0 = tid, e1 = bs1 ? (u1 - 768) : u1, e2 = 256 + tid;
  const int r0 = e0 / 48, c0g = e0 % 48;
  const int r1 = e1 / 48, c1g = e1 % 48;
  const int r2 = e2 / 48, c2g = e2 % 48;
  const int g0 = (row_base + r0) * 96 + c0g;
  const int g1 = (row_base + r1) * 96 + c1g;
  const int g2 = (row_base + r2) * 96 + c2g;
  unsigned short* const L0 = &lds_hi[r0 * LDP + c0g * 8];
  unsigned short* const L1 = bs1 ? &lds_lo[r1 * LDP + c1g * 8]
                                 : &lds_hi[r1 * LDP + c1g * 8];
  unsigned short* const L2 = &lds_lo[r2 * LDP + c2g * 8];

  // GEMM for one kt-slice (6 kt) from LDS; partials write included.
  auto do_gemm = [&](int ksel) {
    f32x4 acc[4] = {{0,0,0,0},{0,0,0,0},{0,0,0,0},{0,0,0,0}};
#pragma unroll
    for (int ktl = 0; ktl < 6; ++ktl) {
      const int kt = ksel * 6 + ktl;
      const s16x8 ah = *(const s16x8*)&lds_hi[frag_off + kt * 32];
      const s16x8 al = *(const s16x8*)&lds_lo[frag_off + kt * 32];
#pragma unroll
      for (int n = 0; n < 4; ++n) {
        acc[n] = __builtin_amdgcn_mfma_f32_16x16x32_bf16(ah, Bhi[ktl][n], acc[n], 0, 0, 0);
        acc[n] = __builtin_amdgcn_mfma_f32_16x16x32_bf16(ah, Blo[ktl][n], acc[n], 0, 0, 0);
        acc[n] = __builtin_amdgcn_mfma_f32_16x16x32_bf16(al, Bhi[ktl][n], acc[n], 0, 0, 0);
      }
    }
    // C/D layout: col = l15, row = quad*4 + reg
#pragma unroll
    for (int n = 0; n < 4; ++n)
#pragma unroll
      for (int reg = 0; reg < 4; ++reg)
        part[colh][ksel][quad * 4 + reg][n * 16 + l15] = acc[n][reg];
  };

  int cur = 0;

  for (int t = 0; t < SS; ++t) {
    const int nxt = (cur == 2) ? 0 : cur + 1;
    const unsigned short* rhi = hbhi[cur];
    const unsigned short* rlo = hblo[cur];
    unsigned short* whi = wbhi[nxt];
    unsigned short* wlo = wblo[nxt];

    if (fast) {
      // ---- split-phase staging: issue all 6 loads, write/compute in halves --
      const uint4v* ph = (const uint4v*)rhi;
      const uint4v* pl = (const uint4v*)rlo;
      const uint4v* p1 = bs1 ? pl : ph;
      const uint4v A0 = ph[g0],      A1 = p1[g1],      A2 = pl[g2];       // K<384
      const uint4v B0 = ph[g0 + 48], B1 = p1[g1 + 48], B2 = pl[g2 + 48];  // K>=384
      *(uint4v*)L0 = A0; *(uint4v*)L1 = A1; *(uint4v*)L2 = A2;
      __syncthreads();                       // S1: K<384 staged
      if (ks < 2) do_gemm(ks);               // slices 0,1 live in K<384
      *(uint4v*)(L0 + 384) = B0; *(uint4v*)(L1 + 384) = B1; *(uint4v*)(L2 + 384) = B2;
      __syncthreads();                       // S2: K>=384 staged
      if (ks >= 2) do_gemm(ks);              // slices 2,3 live in K>=384
    } else {
      // ---- stage group h-slice (16x768 hi+lo) into LDS (agent/MALL loads) --
      const int u64_base = row_base * 192;
#pragma unroll
      for (int i = 0; i < 6; ++i) {
        const int gi = i * 512 + tid;        // u64 idx in [0,3072)
        const int rr = gi / 192, cc = (gi - rr * 192) * 4;
        const unsigned long long vh = __hip_atomic_load(
            (unsigned long long*)rhi + u64_base + gi, __ATOMIC_RELAXED, __HIP_MEMORY_SCOPE_AGENT);
        const unsigned long long vl = __hip_atomic_load(
            (unsigned long long*)rlo + u64_base + gi, __ATOMIC_RELAXED, __HIP_MEMORY_SCOPE_AGENT);
        *(unsigned long long*)&lds_hi[rr * LDP + cc] = vh;
        *(unsigned long long*)&lds_lo[rr * LDP + cc] = vl;
      }
      __syncthreads();
      do_gemm(ks);
    }
    __syncthreads();                         // S3: all partials visible

    // ---- reduce over ks + bias + x*w0; elementwise; h store (1 cell/thr) --
    {
      const f32x4 s0 = *(const f32x4*)&part[ch_c][0][lr_c][c4_c];
      const f32x4 s1 = *(const f32x4*)&part[ch_c][1][lr_c][c4_c];
      const f32x4 s2 = *(const f32x4*)&part[ch_c][2][lr_c][c4_c];
      const f32x4 s3 = *(const f32x4*)&part[ch_c][3][lr_c][c4_c];
      const float xv = x_lds[lr_c];
      f32x4 gv = (s0 + s1) + (s2 + s3);
#pragma unroll
      for (int j = 0; j < 4; ++j) gv[j] += bq[j] + xv * wq[j];

      float cc = c_lds[lr_c][lc_c];
      cc = sigm(gv[1]) * cc + sigm(gv[0]) * tanhf_(gv[2]);
      const float hh = gv[3] * tanhf_(cc);   // no sigmoid on o-gate (ref)
      c_lds[lr_c][lc_c] = cc;

      const unsigned short mhi = f2bf(hh);
      const unsigned short mlo = f2bf(hh - bf2f(mhi));
      const unsigned ohi = (unsigned)__shfl_down((int)(unsigned)mhi, 1, 64);
      const unsigned olo = (unsigned)__shfl_down((int)(unsigned)mlo, 1, 64);
      if ((tid & 1) == 0) {                  // lc_c even; neighbor = lc_c+1
        const int gidx = (row_base + lr_c) * HH + hcol_base + lc_c;
        const unsigned ph2 = (unsigned)mhi | (ohi << 16);
        const unsigned pl2 = (unsigned)mlo | (olo << 16);
        if (fast) {                          // write-through L1 -> XCD L2
          ((unsigned*)whi)[gidx >> 1] = ph2;
          ((unsigned*)wlo)[gidx >> 1] = pl2;
        } else {
          __hip_atomic_store((unsigned*)whi + (gidx >> 1), ph2, __ATOMIC_RELAXED, __HIP_MEMORY_SCOPE_AGENT);
          __hip_atomic_store((unsigned*)wlo + (gidx >> 1), pl2, __ATOMIC_RELAXED, __HIP_MEMORY_SCOPE_AGENT);
        }
      }
      if (tid < 16 && t + 1 < SS) {
        const int row = row_base + tid;
        x_lds[tid] = xin[(row >> 1) * (SS * 2) + (t + 1) * 2 + (row & 1)];
      }
    }
    gbar();
    cur = nxt;
  }

  // ---- output projection: final h in parity cur = 256%3 = 1 ----
  if (p == 0 && tid < 256) {
    const unsigned short* fhi = hbhi[cur];
    const unsigned short* flo = hblo[cur];
    const int rloc = tid >> 4, s = tid & 15;
    const int row = row_base + rloc;
    float sum = 0.0f;
#pragma unroll
    for (int i = 0; i < 12; ++i) {
      const int u = row * 192 + s * 12 + i;  // u64 idx; k0 = s*48 + i*4
      unsigned long long vh, vl;
      if (fast) {                            // fresh in this XCD's L2
        vh = *((const unsigned long long*)fhi + u);
        vl = *((const unsigned long long*)flo + u);
      } else {
        vh = __hip_atomic_load((unsigned long long*)fhi + u, __ATOMIC_RELAXED, __HIP_MEMORY_SCOPE_AGENT);
        vl = __hip_atomic_load((unsigned long long*)flo + u, __ATOMIC_RELAXED, __HIP_MEMORY_SCOPE_AGENT);
      }
#pragma unroll
      for (int j = 0; j < 4; ++j) {
        const float h = bf2f((unsigned short)(vh >> (16 * j))) +
                        bf2f((unsigned short)(vl >> (16 * j)));
        sum += h * Wout[s * 48 + i * 4 + j];
      }
    }
#pragma unroll
    for (int off = 8; off; off >>= 1) sum += __shfl_down(sum, off, 16);
    if (s == 0) out[row] = sum + bout[0];
  }
}

extern "C" void kernel_launch(void* const* d_in, const int* in_sizes, int n_in,
                              void* d_out, int out_size, void* d_ws, size_t ws_size,
                              hipStream_t stream) {
  const float* xin  = (const float*)d_in[0];
  const float* h0   = (const float*)d_in[1];
  const float* c0   = (const float*)d_in[2];
  const float* Wi   = (const float*)d_in[3];
  const float* bi   = (const float*)d_in[4];
  const float* Wf   = (const float*)d_in[5];
  const float* bfv  = (const float*)d_in[6];
  const float* Wc   = (const float*)d_in[7];
  const float* bc   = (const float*)d_in[8];
  const float* Wo   = (const float*)d_in[9];
  const float* bo   = (const float*)d_in[10];
  const float* Wout = (const float*)d_in[11];
  const float* bout = (const float*)d_in[12];
  float* out = (float*)d_out;

  char* ws = (char*)d_ws;
  const size_t HB = (size_t)NROW * HH * sizeof(unsigned short);  // 196608
  unsigned short* hhi0 = (unsigned short*)(ws);
  unsigned short* hhi1 = (unsigned short*)(ws + HB);
  unsigned short* hhi2 = (unsigned short*)(ws + 2 * HB);
  unsigned short* hlo0 = (unsigned short*)(ws + 3 * HB);
  unsigned short* hlo1 = (unsigned short*)(ws + 4 * HB);
  unsigned short* hlo2 = (unsigned short*)(ws + 5 * HB);
  unsigned*       bar  = (unsigned*)(ws + 6 * HB);

  hipMemsetAsync(bar, 0, 4096, stream);    // zero barrier/rendezvous counters

  (void)in_sizes; (void)n_in; (void)out_size; (void)ws_size;
  hipLaunchKernelGGL(lstm_persistent, dim3(GR * GP), dim3(512), 0, stream,
                     xin, h0, c0, Wi, bi, Wf, bfv, Wc, bc, Wo, bo,
                     Wout, bout, out, hhi0, hhi1, hhi2, hlo0, hlo1, hlo2, bar);
}

// Round 5
// 830.486 us; speedup vs baseline: 1.5375x; 1.3805x over previous
//
#include <hip/hip_runtime.h>

typedef float f32x4 __attribute__((ext_vector_type(4)));
typedef short s16x8 __attribute__((ext_vector_type(8)));
typedef unsigned uint4v __attribute__((ext_vector_type(4)));

#define HH   768
#define SS   256
#define GR   8     // row groups (16 rows each); g = blockIdx & 7
#define GP   24    // col blocks per group; p = blockIdx >> 3
#define NROW 128
#define LDP  776   // LDS row pitch (shorts); 1552B = 16B-aligned rows
#define PP   68    // partials row pitch (floats)

__device__ __forceinline__ unsigned short f2bf(float f) {
  unsigned int u = __float_as_uint(f);
  u += 0x7FFFu + ((u >> 16) & 1u);          // RTNE
  return (unsigned short)(u >> 16);
}
__device__ __forceinline__ float bf2f(unsigned short s) {
  return __uint_as_float(((unsigned int)s) << 16);
}
__device__ __forceinline__ float sigm(float v) { return 1.0f / (1.0f + __expf(-v)); }
__device__ __forceinline__ float tanhf_(float v) {
  return 1.0f - 2.0f / (__expf(2.0f * v) + 1.0f);
}

// 192 blocks x 512 threads (8 waves, 2/SIMD via launch_bounds(512,2)).
// Static roles: g = blockIdx&7 (rows [16g,16g+16)), p = blockIdx>>3 (hidden
// cols [32p,32p+32)); gate cols permuted col = hcol*4 + gate.
// Wave w: colh = w&1 (64-gate-col half), ks = w>>1 (6-kt slice of K).
// R12: h transported in bf16 ONLY (h_lo pipeline deleted). GEMM keeps TWO
// MFMA terms per (ktl,n): h_hi*W_hi + h_hi*W_lo — weights stay ~f32 via the
// register-resident Blo; only the h_lo*W_hi term (and with it ALL lo
// staging/LDS/store/convert work) is dropped. Est. error ~1e-3 (h_lo<=2^-9|h|,
// contractive gates). Saves per step: 3 u128 staging loads + 24KB LDS wr/rd,
// 24 of 72 MFMAs/wave, lo-epilogue (f2bf+shfl+store), half the h stores.
// R10 (direct-L2 A) and R11 (split staging, sleepless poll) both regressed
// and are reverted: staged LDS + R6 barrier restored verbatim.
// Transport/sync: R6-proven — XCC_ID vote gating write-through stores +
// plain loads in the XCD L2 (3 parities defeat stale L1), agent-scope
// counter barrier (R8 flag-poll and R9 sc0-poll variants regressed/hung).
__global__ void __launch_bounds__(512, 2) lstm_persistent(
    const float* __restrict__ xin, const float* __restrict__ h0,
    const float* __restrict__ c0,
    const float* __restrict__ Wi, const float* __restrict__ bi,
    const float* __restrict__ Wf, const float* __restrict__ bfv,
    const float* __restrict__ Wc, const float* __restrict__ bc,
    const float* __restrict__ Wo, const float* __restrict__ bo,
    const float* __restrict__ Wout, const float* __restrict__ bout,
    float* __restrict__ out,
    unsigned short* __restrict__ hhi0, unsigned short* __restrict__ hhi1,
    unsigned short* __restrict__ hhi2,
    unsigned short* __restrict__ hlo0, unsigned short* __restrict__ hlo1,
    unsigned short* __restrict__ hlo2,
    unsigned* __restrict__ bar)
{
  const int tid = threadIdx.x, wave = tid >> 6, lane = tid & 63;
  const int l15 = lane & 15, quad = lane >> 4;
  const int g = blockIdx.x & 7, p = blockIdx.x >> 3;
  const int row_base = g * 16, hcol_base = p * 32;
  const int colh = wave & 1, ks = wave >> 1;   // col-half / kt-slice

  __shared__ __align__(16) unsigned short lds_hi[16 * LDP];
  __shared__ __align__(16) float part[2][4][16][PP];   // [colh][ks][row][col64]
  __shared__ float bw_b[128], bw_w[128];               // bias / x-weight per col
  __shared__ float c_lds[16][33];
  __shared__ float x_lds[16];
  __shared__ int s_fast;

  unsigned* ctr = bar + g * 64;              // step barrier (256B-spaced)
  unsigned* rdy = bar + 512 + g * 16;        // rendezvous counter
  unsigned* ids = bar + 640 + g * 32;        // 24 published XCC_IDs

  // ---- one-time vote (tid0): all 24 members on one XCD? [R6-proven] ----
  if (tid == 0) {
    const unsigned my = (__builtin_amdgcn_s_getreg(20 | (3 << 11)) & 15u) + 1u;
    __hip_atomic_store(ids + p, my, __ATOMIC_RELAXED, __HIP_MEMORY_SCOPE_AGENT);
    __hip_atomic_fetch_add(rdy, 1u, __ATOMIC_RELEASE, __HIP_MEMORY_SCOPE_AGENT);
    while (__hip_atomic_load(rdy, __ATOMIC_ACQUIRE, __HIP_MEMORY_SCOPE_AGENT)
           < (unsigned)GP)
      __builtin_amdgcn_s_sleep(8);
    int ok = 1;
    for (int q = 0; q < GP; ++q)
      ok &= (__hip_atomic_load(ids + q, __ATOMIC_RELAXED,
                               __HIP_MEMORY_SCOPE_AGENT) == my);
    s_fast = ok;
  }

  // ---- one-time: weights -> bf16 hi/lo B-fragments (n=lane&15, k=quad*8+j) --
  // Blo (W_lo) kept in registers: weights remain ~f32-accurate at zero
  // transport cost. Only the h-side lo is dropped (R12).
  s16x8 Bhi[6][4], Blo[6][4];
#pragma unroll
  for (int n = 0; n < 4; ++n) {
    const int col = p * 128 + colh * 64 + n * 16 + l15;  // permuted gate col
    const int gg = col & 3, hc = col >> 2;
    const float* W = (gg == 0) ? Wi : (gg == 1) ? Wf : (gg == 2) ? Wc : Wo;
#pragma unroll
    for (int ktl = 0; ktl < 6; ++ktl) {
      const int kt = ks * 6 + ktl;
      s16x8 vh, vl;
#pragma unroll
      for (int j = 0; j < 8; ++j) {
        const int k = kt * 32 + quad * 8 + j;
        const float w = W[(1 + k) * HH + hc];
        const unsigned short hi = f2bf(w);
        vh[j] = (short)hi;
        vl[j] = (short)f2bf(w - bf2f(hi));
      }
      Bhi[ktl][n] = vh; Blo[ktl][n] = vl;
    }
  }

  // ---- one-time: bias + x-weight tables -> LDS (per permuted gate col) ----
  if (tid < 128) {
    const int gg = tid & 3;
    const int hc = p * 32 + (tid >> 2);
    const float* W  = (gg == 0) ? Wi : (gg == 1) ? Wf : (gg == 2) ? Wc : Wo;
    const float* bb = (gg == 0) ? bi : (gg == 1) ? bfv : (gg == 2) ? bc : bo;
    bw_b[tid] = bb[hc];
    bw_w[tid] = W[hc];                       // W row 0 = x weight (exact fp32)
  }

  // ---- init: c->LDS; h0 -> parity-0 hi buffer (agent stores) ----
  if (tid < 256) {
    const int lr = tid >> 4, lc = (tid & 15) * 2;
    const int gidx = (row_base + lr) * HH + hcol_base + lc;
    const float ha = h0[gidx], hb = h0[gidx + 1];
    c_lds[lr][lc]     = c0[gidx];
    c_lds[lr][lc + 1] = c0[gidx + 1];
    const unsigned short ha_hi = f2bf(ha), hb_hi = f2bf(hb);
    __hip_atomic_store((unsigned*)hhi0 + (gidx >> 1),
                       (unsigned)ha_hi | ((unsigned)hb_hi << 16),
                       __ATOMIC_RELAXED, __HIP_MEMORY_SCOPE_AGENT);
    if (tid < 16) {
      const int row = row_base + tid;
      x_lds[tid] = xin[(row >> 1) * (SS * 2) + (row & 1)];   // t = 0
    }
  }
  __syncthreads();                           // s_fast + LDS init visible
  const bool fast = (s_fast != 0);
  unsigned bars = 0;

  // Agent-scope counter barrier (R3/R6-proven; R8/R9/R11 variants failed).
  auto gbar = [&]() {
    __builtin_amdgcn_s_waitcnt(0);
    __syncthreads();
    if (tid == 0) {
      ++bars;
      __hip_atomic_fetch_add(ctr, 1u, __ATOMIC_RELAXED, __HIP_MEMORY_SCOPE_AGENT);
      const unsigned want = (unsigned)GP * bars;
      while (__hip_atomic_load(ctr, __ATOMIC_RELAXED, __HIP_MEMORY_SCOPE_AGENT) < want)
        __builtin_amdgcn_s_sleep(1);
    }
    __syncthreads();
  };

  gbar();                                    // h0/c0 published

  const unsigned short* hbhi[3] = {hhi0, hhi1, hhi2};
  unsigned short* wbhi[3] = {hhi0, hhi1, hhi2};

  const int frag_off = l15 * LDP + quad * 8; // A-frag LDS offset (shorts)
  const int lr_c = tid >> 5, lc_c = tid & 31;        // elementwise cell
  const int ch_c = lc_c >> 4, c4_c = (lc_c & 15) * 4;
  int cur = 0;

  for (int t = 0; t < SS; ++t) {
    const int nxt = (cur == 2) ? 0 : cur + 1;
    const unsigned short* rhi = hbhi[cur];
    unsigned short* whi = wbhi[nxt];

    // ---- stage group h-slice (16x768 hi) into LDS ----
    if (fast) {                              // plain 16B loads from XCD L2
      const uint4v* rh = (const uint4v*)(rhi + row_base * HH);
      uint4v hv[3];
#pragma unroll
      for (int i = 0; i < 3; ++i) {
        const int gi = i * 512 + tid;        // u128 idx in [0,1536)
        hv[i] = rh[gi];
      }
#pragma unroll
      for (int i = 0; i < 3; ++i) {
        const int gi = i * 512 + tid;
        const int rr = gi / 96, cc = (gi - rr * 96) * 8;
        *(uint4v*)&lds_hi[rr * LDP + cc] = hv[i];
      }
    } else {                                 // agent-scope (MALL) loads
      const int u64_base = row_base * 192;
#pragma unroll
      for (int i = 0; i < 6; ++i) {
        const int gi = i * 512 + tid;        // u64 idx in [0,3072)
        const int rr = gi / 192, cc = (gi - rr * 192) * 4;
        const unsigned long long vh = __hip_atomic_load(
            (unsigned long long*)rhi + u64_base + gi, __ATOMIC_RELAXED, __HIP_MEMORY_SCOPE_AGENT);
        *(unsigned long long*)&lds_hi[rr * LDP + cc] = vh;
      }
    }
    __syncthreads();

    // ---- GEMM: wave (colh,ks): 6kt x 4n, 2 MFMA/(ktl,n): h_hi*(W_hi+W_lo) --
    f32x4 acc[4] = {{0,0,0,0},{0,0,0,0},{0,0,0,0},{0,0,0,0}};
#pragma unroll
    for (int ktl = 0; ktl < 6; ++ktl) {
      const int kt = ks * 6 + ktl;
      const s16x8 ah = *(const s16x8*)&lds_hi[frag_off + kt * 32];
#pragma unroll
      for (int n = 0; n < 4; ++n) {
        acc[n] = __builtin_amdgcn_mfma_f32_16x16x32_bf16(ah, Bhi[ktl][n], acc[n], 0, 0, 0);
        acc[n] = __builtin_amdgcn_mfma_f32_16x16x32_bf16(ah, Blo[ktl][n], acc[n], 0, 0, 0);
      }
    }

    // ---- partial write: C/D layout col=l15, row=quad*4+reg ----
#pragma unroll
    for (int n = 0; n < 4; ++n)
#pragma unroll
      for (int reg = 0; reg < 4; ++reg)
        part[colh][ks][quad * 4 + reg][n * 16 + l15] = acc[n][reg];
    __syncthreads();

    // ---- reduce over ks + bias + x*w0; elementwise; h store (1 cell/thr) --
    {
      const f32x4 s0 = *(const f32x4*)&part[ch_c][0][lr_c][c4_c];
      const f32x4 s1 = *(const f32x4*)&part[ch_c][1][lr_c][c4_c];
      const f32x4 s2 = *(const f32x4*)&part[ch_c][2][lr_c][c4_c];
      const f32x4 s3 = *(const f32x4*)&part[ch_c][3][lr_c][c4_c];
      const f32x4 bq = *(const f32x4*)&bw_b[lc_c * 4];
      const f32x4 wq = *(const f32x4*)&bw_w[lc_c * 4];
      const float xv = x_lds[lr_c];
      f32x4 gv = (s0 + s1) + (s2 + s3);
#pragma unroll
      for (int j = 0; j < 4; ++j) gv[j] += bq[j] + xv * wq[j];

      float cc = c_lds[lr_c][lc_c];
      cc = sigm(gv[1]) * cc + sigm(gv[0]) * tanhf_(gv[2]);
      const float hh = gv[3] * tanhf_(cc);   // no sigmoid on o-gate (ref)
      c_lds[lr_c][lc_c] = cc;

      const unsigned short mhi = f2bf(hh);
      const unsigned ohi = (unsigned)__shfl_down((int)(unsigned)mhi, 1, 64);
      if ((tid & 1) == 0) {                  // lc_c even; neighbor = lc_c+1
        const int gidx = (row_base + lr_c) * HH + hcol_base + lc_c;
        const unsigned ph = (unsigned)mhi | (ohi << 16);
        if (fast) {                          // write-through L1 -> XCD L2
          ((unsigned*)whi)[gidx >> 1] = ph;
        } else {
          __hip_atomic_store((unsigned*)whi + (gidx >> 1), ph, __ATOMIC_RELAXED, __HIP_MEMORY_SCOPE_AGENT);
        }
      }
      if (tid < 16 && t + 1 < SS) {
        const int row = row_base + tid;
        x_lds[tid] = xin[(row >> 1) * (SS * 2) + (t + 1) * 2 + (row & 1)];
      }
    }
    gbar();
    cur = nxt;
  }

  // ---- output projection: final h in parity cur = 256%3 = 1 ----
  if (p == 0 && tid < 256) {
    const unsigned short* fhi = hbhi[cur];
    const int rloc = tid >> 4, s = tid & 15;
    const int row = row_base + rloc;
    float sum = 0.0f;
#pragma unroll
    for (int i = 0; i < 12; ++i) {
      const int u = row * 192 + s * 12 + i;  // u64 idx; k0 = s*48 + i*4
      unsigned long long vh;
      if (fast) {                            // fresh in this XCD's L2
        vh = *((const unsigned long long*)fhi + u);
      } else {
        vh = __hip_atomic_load((unsigned long long*)fhi + u, __ATOMIC_RELAXED, __HIP_MEMORY_SCOPE_AGENT);
      }
#pragma unroll
      for (int j = 0; j < 4; ++j) {
        const float h = bf2f((unsigned short)(vh >> (16 * j)));
        sum += h * Wout[s * 48 + i * 4 + j];
      }
    }
#pragma unroll
    for (int off = 8; off; off >>= 1) sum += __shfl_down(sum, off, 16);
    if (s == 0) out[row] = sum + bout[0];
  }
}

extern "C" void kernel_launch(void* const* d_in, const int* in_sizes, int n_in,
                              void* d_out, int out_size, void* d_ws, size_t ws_size,
                              hipStream_t stream) {
  const float* xin  = (const float*)d_in[0];
  const float* h0   = (const float*)d_in[1];
  const float* c0   = (const float*)d_in[2];
  const float* Wi   = (const float*)d_in[3];
  const float* bi   = (const float*)d_in[4];
  const float* Wf   = (const float*)d_in[5];
  const float* bfv  = (const float*)d_in[6];
  const float* Wc   = (const float*)d_in[7];
  const float* bc   = (const float*)d_in[8];
  const float* Wo   = (const float*)d_in[9];
  const float* bo   = (const float*)d_in[10];
  const float* Wout = (const float*)d_in[11];
  const float* bout = (const float*)d_in[12];
  float* out = (float*)d_out;

  char* ws = (char*)d_ws;
  const size_t HB = (size_t)NROW * HH * sizeof(unsigned short);  // 196608
  unsigned short* hhi0 = (unsigned short*)(ws);
  unsigned short* hhi1 = (unsigned short*)(ws + HB);
  unsigned short* hhi2 = (unsigned short*)(ws + 2 * HB);
  unsigned short* hlo0 = (unsigned short*)(ws + 3 * HB);
  unsigned short* hlo1 = (unsigned short*)(ws + 4 * HB);
  unsigned short* hlo2 = (unsigned short*)(ws + 5 * HB);
  unsigned*       bar  = (unsigned*)(ws + 6 * HB);

  hipMemsetAsync(bar, 0, 4096, stream);    // zero barrier/rendezvous counters

  (void)in_sizes; (void)n_in; (void)out_size; (void)ws_size;
  hipLaunchKernelGGL(lstm_persistent, dim3(GR * GP), dim3(512), 0, stream,
                     xin, h0, c0, Wi, bi, Wf, bfv, Wc, bc, Wo, bo,
                     Wout, bout, out, hhi0, hhi1, hhi2, hlo0, hlo1, hlo2, bar);
}